// Round 7
// baseline (366.858 us; speedup 1.0000x reference)
//
#include <hip/hip_runtime.h>
#include <stdint.h>

// ---------------------------------------------------------------------------
// Encoder block, MI355X bf16-MFMA (round 7: 8-wave 128x128 GEMM with 3-deep
// LDS pipeline, counted vmcnt(4) across a single barrier per K-tile, setprio
// around MFMA cluster).  Quirks: k = q (query projection), scale = 768^-0.5.
// ---------------------------------------------------------------------------

typedef __attribute__((ext_vector_type(8))) short s8v;      // 8 x bf16
typedef __attribute__((ext_vector_type(4))) float f32x4;    // MFMA C/D frag
typedef __attribute__((ext_vector_type(4))) unsigned short us4v;

__device__ __forceinline__ unsigned short f2b(float f) {  // f32 -> bf16 RTNE
  union { float f; unsigned u; } v; v.f = f;
  unsigned r = v.u + 0x7FFFu + ((v.u >> 16) & 1u);
  return (unsigned short)(r >> 16);
}

__device__ __forceinline__ void g2l16(const unsigned short* g, unsigned short* l) {
  __builtin_amdgcn_global_load_lds(
      (const __attribute__((address_space(1))) unsigned int*)g,
      (__attribute__((address_space(3))) unsigned int*)l, 16, 0, 0);
}

// sqrt(768^-0.5 * log2(e)): folded into BOTH q and k (same tensor, k=q quirk)
#define QSCALE 0.22816534f

// ---------------- weight repack: all weights -> bf16, B^T [N][K] layout ------
__global__ __launch_bounds__(256) void repack_kernel(
    const float* __restrict__ Wq, const float* __restrict__ bq,
    const float* __restrict__ Wv, const float* __restrict__ bv,
    const float* __restrict__ Wo, const float* __restrict__ W1,
    const float* __restrict__ W2,
    unsigned short* __restrict__ Wqv_t, float* __restrict__ bias_qv,
    unsigned short* __restrict__ Wo_t, unsigned short* __restrict__ W1_t,
    unsigned short* __restrict__ W2_t)
{
  int i = blockIdx.x * 256 + threadIdx.x;
  if (i < 1536 * 768) {
    int n = i / 768, d = i % 768;
    float val;
    if (n < 768) { int h = n >> 6, e = n & 63; val = Wq[(h * 768 + d) * 64 + e] * QSCALE; }
    else { int c = n - 768; int h = c >> 6, e = c & 63; val = Wv[(h * 768 + d) * 64 + e]; }
    Wqv_t[i] = f2b(val);
  }
  if (i < 1536) bias_qv[i] = (i < 768) ? bq[i] * QSCALE : bv[i - 768];
  if (i < 768 * 768)  { int n = i / 768,  k = i % 768;  Wo_t[i] = f2b(Wo[k * 768  + n]); }
  if (i < 3072 * 768) { int n = i / 768,  k = i % 768;  W1_t[i] = f2b(W1[k * 3072 + n]); }
  if (i < 768 * 3072) { int n = i / 3072, k = i % 3072; W2_t[i] = f2b(W2[k * 768  + n]); }
}

// ---------------- LayerNorm: f32 [8192][768] -> bf16 ------------------------
__global__ __launch_bounds__(256) void ln_kernel(
    const float* __restrict__ x, const float* __restrict__ g,
    const float* __restrict__ b, unsigned short* __restrict__ out)
{
  __shared__ float red[4], red2[4];
  int row = blockIdx.x, t = threadIdx.x;
  const float* xr = x + (size_t)row * 768;
  float v0 = xr[t], v1 = xr[t + 256], v2 = xr[t + 512];
  float s = v0 + v1 + v2;
  #pragma unroll
  for (int m = 32; m; m >>= 1) s += __shfl_xor(s, m);
  if ((t & 63) == 0) red[t >> 6] = s;
  __syncthreads();
  float mean = (red[0] + red[1] + red[2] + red[3]) * (1.f / 768.f);
  float d0 = v0 - mean, d1 = v1 - mean, d2 = v2 - mean;
  float vs = d0 * d0 + d1 * d1 + d2 * d2;
  #pragma unroll
  for (int m = 32; m; m >>= 1) vs += __shfl_xor(vs, m);
  if ((t & 63) == 0) red2[t >> 6] = vs;
  __syncthreads();
  float var = (red2[0] + red2[1] + red2[2] + red2[3]) * (1.f / 768.f);
  float rs = rsqrtf(var + 1e-5f);
  unsigned short* o = out + (size_t)row * 768;
  o[t]       = f2b(d0 * rs * g[t]       + b[t]);
  o[t + 256] = f2b(d1 * rs * g[t + 256] + b[t + 256]);
  o[t + 512] = f2b(d2 * rs * g[t + 512] + b[t + 512]);
}

// ---------------- 8-wave 128x128 GEMM, 3-deep counted-vmcnt pipeline ---------
// 512 thr = 8 waves (2m x 4n), wave tile 64x32 (acc 4x2), BK=64.
// 3 LDS buffers (96 KiB).  Per K-tile t:
//   vmcnt(4) [t+1's 4 loads stay in flight] -> s_barrier ->
//   issue stage(t+2) -> ds_read(t) -> setprio(1) 16 MFMA setprio(0).
// Safety: stage(t+2) writes buf[(t-1)%3] AFTER barrier(t); all iter-(t-1)
// ds_reads were consumed before their MFMAs, hence before barrier(t).
// Both-sides XOR swizzle; XCD-chunked, n-fastest block map.
// EPI: 1 = f32 out = resid + acc + bias; 2 = bf16 tanh-gelu; 3 = qv split.
template<int EPI, int N, int K>
__global__ __launch_bounds__(512, 1) void gemm8w(
    const unsigned short* __restrict__ A, const unsigned short* __restrict__ Bt,
    const float* __restrict__ bias,
    const float* resid, float* out_f32,
    unsigned short* __restrict__ out_bf,
    unsigned short* __restrict__ q_out, unsigned short* __restrict__ vt_out)
{
  __shared__ __align__(16) unsigned short As_[3][8192];
  __shared__ __align__(16) unsigned short Bs_[3][8192];
  constexpr int NTN = N >> 7;
  constexpr int NT = K >> 6;
  int bid = blockIdx.x;
  int q8 = gridDim.x >> 3;                      // grids are %8==0
  int sb = (bid & 7) * q8 + (bid >> 3);         // XCD-chunked, n fastest
  int m0 = (sb / NTN) << 7, n0 = (sb % NTN) << 7;
  int t = threadIdx.x, lane = t & 63, w = t >> 6;   // w 0..7
  int l15 = lane & 15, lg = lane >> 4;
  int wm = (w >> 2) << 6;                       // 0 / 64
  int wn = (w & 3) << 5;                        // 0 / 32 / 64 / 96
  int lxor = ((lane & 7) ^ (lane >> 3)) << 3;   // pre-swizzled src col
  int srow = w * 16 + (lane >> 3);              // staging row, j=0
  const unsigned short* Abase = A + (size_t)m0 * K;
  const unsigned short* Bbase = Bt + (size_t)n0 * K;

  auto stage = [&](int buf, int tile) {
    int k0 = tile << 6;
    #pragma unroll
    for (int j = 0; j < 2; ++j) {               // 4 loads/thread: A0,B0,A1,B1
      g2l16(&Abase[(size_t)(srow + j * 8) * K + k0 + lxor],
            &As_[buf][(w * 16 + j * 8) * 64]);
      g2l16(&Bbase[(size_t)(srow + j * 8) * K + k0 + lxor],
            &Bs_[buf][(w * 16 + j * 8) * 64]);
    }
  };

  f32x4 acc[4][2] = {};
  stage(0, 0);
  stage(1, 1);
  int cswz = (l15 & 7) << 3;
  #pragma unroll 3
  for (int tt = 0; tt < NT; ++tt) {
    if (tt + 1 < NT) { asm volatile("s_waitcnt vmcnt(4)" ::: "memory"); }
    else             { asm volatile("s_waitcnt vmcnt(0)" ::: "memory"); }
    __builtin_amdgcn_sched_barrier(0);
    __builtin_amdgcn_s_barrier();
    __builtin_amdgcn_sched_barrier(0);
    if (tt + 2 < NT) stage((tt + 2) % 3, tt + 2);
    __builtin_amdgcn_sched_barrier(0);
    const unsigned short* Ac = &As_[tt % 3][0];
    const unsigned short* Bc = &Bs_[tt % 3][0];
    s8v a[4][2], b[2][2];
    #pragma unroll
    for (int kk = 0; kk < 2; ++kk) {
      int col = (kk * 32 + lg * 8) ^ cswz;
      #pragma unroll
      for (int i = 0; i < 4; ++i) a[i][kk] = *(const s8v*)&Ac[(wm + i * 16 + l15) * 64 + col];
      #pragma unroll
      for (int i = 0; i < 2; ++i) b[i][kk] = *(const s8v*)&Bc[(wn + i * 16 + l15) * 64 + col];
    }
    __builtin_amdgcn_s_setprio(1);
    #pragma unroll
    for (int kk = 0; kk < 2; ++kk)
      #pragma unroll
      for (int mi = 0; mi < 4; ++mi)
        #pragma unroll
        for (int ni = 0; ni < 2; ++ni)
          acc[mi][ni] = __builtin_amdgcn_mfma_f32_16x16x32_bf16(a[mi][kk], b[ni][kk], acc[mi][ni], 0, 0, 0);
    __builtin_amdgcn_s_setprio(0);
  }
  // ---- epilogue ----
  #pragma unroll
  for (int mi = 0; mi < 4; ++mi) {
    #pragma unroll
    for (int ni = 0; ni < 2; ++ni) {
      int col = n0 + wn + ni * 16 + l15;
      float bs = bias[col];
      #pragma unroll
      for (int r = 0; r < 4; ++r) {
        int row = m0 + wm + mi * 16 + lg * 4 + r;
        float v = acc[mi][ni][r] + bs;
        if (EPI == 1) {
          out_f32[(size_t)row * N + col] = resid[(size_t)row * N + col] + v;
        } else if (EPI == 2) {
          // tanh-gelu via exp2: v * sigmoid(1.5957688(v + 0.044715 v^3))
          float v2 = v * v;
          float z = v * fmaf(-0.10294202f, v2, -2.302026f);
          float e; asm("v_exp_f32 %0, %1" : "=v"(e) : "v"(z));
          float rcp; asm("v_rcp_f32 %0, %1" : "=v"(rcp) : "v"(e + 1.0f));
          out_bf[(size_t)row * N + col] = f2b(v * rcp);
        } else { // EPI == 3
          if (col < 768) {
            q_out[(size_t)row * 768 + col] = f2b(v);
          } else {
            int c = col - 768; int hh = c >> 6, e = c & 63;
            int bb = row >> 10, s = row & 1023;
            vt_out[(((size_t)(bb * 12 + hh)) * 64 + e) * 1024 + s] = f2b(v);
          }
        }
      }
    }
  }
}

// ---------------- fused attention (k = q quirk; scale folded into q_bf) ------
__global__ __launch_bounds__(256) void attn_kernel(
    const unsigned short* __restrict__ qk,  // [8192][768] (q == k, pre-scaled)
    const unsigned short* __restrict__ vt,  // [96][64][1024]
    unsigned short* __restrict__ o)         // [8192][768]
{
  __shared__ __align__(16) unsigned short Qs[128 * 64];
  __shared__ __align__(16) unsigned short Ks[2][64 * 64];
  __shared__ __align__(16) unsigned short Vs[2][64 * 64];
  __shared__ __align__(16) unsigned short Ps[128 * 64];
  int bid = blockIdx.x;
  int xcd = bid & 7, idx = bid >> 3;
  int bh = xcd * 12 + (idx >> 3), qt = idx & 7;
  int b = bh / 12, h = bh % 12;
  int t = threadIdx.x, lane = t & 63, w = t >> 6;
  int l15 = lane & 15, lg = lane >> 4;
  int wq0 = w << 5;
  size_t qrow0 = (size_t)b * 1024 + qt * 128;
  size_t krow0 = (size_t)b * 1024;
  size_t vbase = ((size_t)bh) * 64 * 1024;

  int srow = t >> 3;
  int scsw = ((t & 7) << 3) ^ ((srow & 7) << 3);
  const unsigned short* qsrc = &qk[(qrow0 + srow) * 768 + h * 64 + scsw];
  const unsigned short* ksrc = &qk[(krow0 + srow) * 768 + h * 64 + scsw];
  const unsigned short* vsrc = &vt[vbase + (size_t)srow * 1024 + scsw];

  #pragma unroll
  for (int j = 0; j < 4; ++j)
    g2l16(qsrc + (size_t)j * 32 * 768, &Qs[(j * 256 + w * 64) * 8]);
  #pragma unroll
  for (int j = 0; j < 2; ++j) {
    g2l16(ksrc + (size_t)j * 32 * 768, &Ks[0][(j * 256 + w * 64) * 8]);
    g2l16(vsrc + (size_t)j * 32 * 1024, &Vs[0][(j * 256 + w * 64) * 8]);
  }
  asm volatile("s_waitcnt vmcnt(0)" ::: "memory");
  __builtin_amdgcn_s_barrier();

  f32x4 oacc[4][2] = {};
  float lsum[2] = {0.f, 0.f};
  int cswz = (l15 & 7) << 3;

  for (int kt = 0; kt < 16; ++kt) {
    int buf = kt & 1;
    if (kt < 15) {
      const unsigned short* kp = ksrc + (size_t)(kt + 1) * 64 * 768;
      const unsigned short* vp = vsrc + (kt + 1) * 64;
      #pragma unroll
      for (int j = 0; j < 2; ++j) {
        g2l16(kp + (size_t)j * 32 * 768, &Ks[buf ^ 1][(j * 256 + w * 64) * 8]);
        g2l16(vp + (size_t)j * 32 * 1024, &Vs[buf ^ 1][(j * 256 + w * 64) * 8]);
      }
    }
    const unsigned short* Kb = Ks[buf];
    const unsigned short* Vb = Vs[buf];
    f32x4 st[4][2] = {};
    #pragma unroll
    for (int kk = 0; kk < 2; ++kk) {
      int col = (kk * 32 + lg * 8) ^ cswz;
      s8v a[4], bq2[2];
      #pragma unroll
      for (int i = 0; i < 4; ++i) a[i] = *(const s8v*)&Kb[(i * 16 + l15) * 64 + col];
      #pragma unroll
      for (int i = 0; i < 2; ++i) bq2[i] = *(const s8v*)&Qs[(wq0 + i * 16 + l15) * 64 + col];
      #pragma unroll
      for (int mi = 0; mi < 4; ++mi)
        #pragma unroll
        for (int ni = 0; ni < 2; ++ni)
          st[mi][ni] = __builtin_amdgcn_mfma_f32_16x16x32_bf16(a[mi], bq2[ni], st[mi][ni], 0, 0, 0);
    }
    #pragma unroll
    for (int ni = 0; ni < 2; ++ni) {
      int prow = (wq0 + ni * 16 + l15) * 64;
      #pragma unroll
      for (int mi = 0; mi < 4; ++mi) {
        float p0, p1, p2, p3;
        asm("v_exp_f32 %0, %1" : "=v"(p0) : "v"(st[mi][ni][0]));
        asm("v_exp_f32 %0, %1" : "=v"(p1) : "v"(st[mi][ni][1]));
        asm("v_exp_f32 %0, %1" : "=v"(p2) : "v"(st[mi][ni][2]));
        asm("v_exp_f32 %0, %1" : "=v"(p3) : "v"(st[mi][ni][3]));
        lsum[ni] += (p0 + p1) + (p2 + p3);
        unsigned lo, hi;
        asm("v_cvt_pk_bf16_f32 %0, %1, %2" : "=v"(lo) : "v"(p0), "v"(p1));
        asm("v_cvt_pk_bf16_f32 %0, %1, %2" : "=v"(hi) : "v"(p2), "v"(p3));
        unsigned long long pk = (unsigned long long)lo | ((unsigned long long)hi << 32);
        *(unsigned long long*)&Ps[prow + ((mi * 16 + lg * 4) ^ cswz)] = pk;
      }
    }
    #pragma unroll
    for (int kk = 0; kk < 2; ++kk) {
      int col = (kk * 32 + lg * 8) ^ cswz;
      s8v a[4], bp[2];
      #pragma unroll
      for (int i = 0; i < 4; ++i) a[i] = *(const s8v*)&Vb[(i * 16 + l15) * 64 + col];
      #pragma unroll
      for (int i = 0; i < 2; ++i) bp[i] = *(const s8v*)&Ps[(wq0 + i * 16 + l15) * 64 + col];
      #pragma unroll
      for (int ei = 0; ei < 4; ++ei)
        #pragma unroll
        for (int ni = 0; ni < 2; ++ni)
          oacc[ei][ni] = __builtin_amdgcn_mfma_f32_16x16x32_bf16(a[ei], bp[ni], oacc[ei][ni], 0, 0, 0);
    }
    asm volatile("s_waitcnt vmcnt(0)" ::: "memory");
    __builtin_amdgcn_s_barrier();
  }
  #pragma unroll
  for (int ni = 0; ni < 2; ++ni) {
    float s = lsum[ni];
    s += __shfl_xor(s, 16);
    s += __shfl_xor(s, 32);
    float inv = 1.f / s;
    int q = wq0 + ni * 16 + l15;
    size_t obase = (qrow0 + q) * 768 + h * 64;
    #pragma unroll
    for (int ei = 0; ei < 4; ++ei) {
      us4v ov;
      #pragma unroll
      for (int r = 0; r < 4; ++r) ov[r] = f2b(oacc[ei][ni][r] * inv);
      *(us4v*)&o[obase + ei * 16 + lg * 4] = ov;
    }
  }
}

// ---------------------------------------------------------------------------
extern "C" void kernel_launch(void* const* d_in, const int* in_sizes, int n_in,
                              void* d_out, int out_size, void* d_ws, size_t ws_size,
                              hipStream_t stream)
{
  const float* x     = (const float*)d_in[0];
  const float* ln1_g = (const float*)d_in[1];
  const float* ln1_b = (const float*)d_in[2];
  const float* Wq    = (const float*)d_in[3];
  const float* bq    = (const float*)d_in[4];
  const float* Wv    = (const float*)d_in[5];
  const float* bv    = (const float*)d_in[6];
  const float* Wo    = (const float*)d_in[7];
  const float* bo    = (const float*)d_in[8];
  const float* ln2_g = (const float*)d_in[9];
  const float* ln2_b = (const float*)d_in[10];
  const float* W1    = (const float*)d_in[11];
  const float* b1    = (const float*)d_in[12];
  const float* W2    = (const float*)d_in[13];
  const float* b2    = (const float*)d_in[14];
  float* out = (float*)d_out;

  char* ws = (char*)d_ws;
  size_t off = 0;
  auto alloc = [&](size_t bytes) -> void* {
    void* p = ws + off; off += (bytes + 255) & ~(size_t)255; return p;
  };
  unsigned short* Wqv_t  = (unsigned short*)alloc(1536ull * 768 * 2);
  float*          bias_qv= (float*)         alloc(1536ull * 4);
  unsigned short* Wo_t   = (unsigned short*)alloc(768ull * 768 * 2);
  unsigned short* W1_t   = (unsigned short*)alloc(3072ull * 768 * 2);
  unsigned short* W2_t   = (unsigned short*)alloc(768ull * 3072 * 2);
  unsigned short* h_bf   = (unsigned short*)alloc(8192ull * 768 * 2);
  unsigned short* q_bf   = (unsigned short*)alloc(8192ull * 768 * 2);
  unsigned short* v_t    = (unsigned short*)alloc(96ull * 64 * 1024 * 2);
  unsigned short* o_bf   = (unsigned short*)alloc(8192ull * 768 * 2);
  unsigned short* h2_bf  = (unsigned short*)alloc(8192ull * 768 * 2);
  unsigned short* m1_bf  = (unsigned short*)alloc(8192ull * 3072 * 2);

  repack_kernel<<<9216, 256, 0, stream>>>(Wq, bq, Wv, bv, Wo, W1, W2,
                                          Wqv_t, bias_qv, Wo_t, W1_t, W2_t);
  ln_kernel<<<8192, 256, 0, stream>>>(x, ln1_g, ln1_b, h_bf);
  gemm8w<3, 1536, 768><<<768, 512, 0, stream>>>(h_bf, Wqv_t, bias_qv,
      nullptr, nullptr, nullptr, q_bf, v_t);
  attn_kernel<<<768, 256, 0, stream>>>(q_bf, v_t, o_bf);
  gemm8w<1, 768, 768><<<384, 512, 0, stream>>>(o_bf, Wo_t, bo,
      x, out, nullptr, nullptr, nullptr);
  ln_kernel<<<8192, 256, 0, stream>>>(out, ln2_g, ln2_b, h2_bf);
  gemm8w<2, 3072, 768><<<1536, 512, 0, stream>>>(h2_bf, W1_t, b1,
      nullptr, nullptr, m1_bf, nullptr, nullptr);
  gemm8w<1, 768, 3072><<<384, 512, 0, stream>>>(m1_bf, W2_t, b2,
      out, out, nullptr, nullptr, nullptr);
}

// Round 8
// 308.212 us; speedup vs baseline: 1.1903x; 1.1903x over previous
//
#include <hip/hip_runtime.h>
#include <stdint.h>

// ---------------------------------------------------------------------------
// Encoder block, MI355X bf16-MFMA (round 8: 4-wave 128x128 GEMM, 2 blocks/CU,
// counted vmcnt(8) pipeline -- next tile's loads stay in flight across the
// barrier; n-fastest XCD-chunked map).  Quirks: k = q, scale = 768^-0.5.
// ---------------------------------------------------------------------------

typedef __attribute__((ext_vector_type(8))) short s8v;      // 8 x bf16
typedef __attribute__((ext_vector_type(4))) float f32x4;    // MFMA C/D frag
typedef __attribute__((ext_vector_type(4))) unsigned short us4v;

__device__ __forceinline__ unsigned short f2b(float f) {  // f32 -> bf16 RTNE
  union { float f; unsigned u; } v; v.f = f;
  unsigned r = v.u + 0x7FFFu + ((v.u >> 16) & 1u);
  return (unsigned short)(r >> 16);
}

__device__ __forceinline__ void g2l16(const unsigned short* g, unsigned short* l) {
  __builtin_amdgcn_global_load_lds(
      (const __attribute__((address_space(1))) unsigned int*)g,
      (__attribute__((address_space(3))) unsigned int*)l, 16, 0, 0);
}

// sqrt(768^-0.5 * log2(e)): folded into BOTH q and k (same tensor, k=q quirk)
#define QSCALE 0.22816534f

// ---------------- weight repack: all weights -> bf16, B^T [N][K] layout ------
__global__ __launch_bounds__(256) void repack_kernel(
    const float* __restrict__ Wq, const float* __restrict__ bq,
    const float* __restrict__ Wv, const float* __restrict__ bv,
    const float* __restrict__ Wo, const float* __restrict__ W1,
    const float* __restrict__ W2,
    unsigned short* __restrict__ Wqv_t, float* __restrict__ bias_qv,
    unsigned short* __restrict__ Wo_t, unsigned short* __restrict__ W1_t,
    unsigned short* __restrict__ W2_t)
{
  int i = blockIdx.x * 256 + threadIdx.x;
  if (i < 1536 * 768) {
    int n = i / 768, d = i % 768;
    float val;
    if (n < 768) { int h = n >> 6, e = n & 63; val = Wq[(h * 768 + d) * 64 + e] * QSCALE; }
    else { int c = n - 768; int h = c >> 6, e = c & 63; val = Wv[(h * 768 + d) * 64 + e]; }
    Wqv_t[i] = f2b(val);
  }
  if (i < 1536) bias_qv[i] = (i < 768) ? bq[i] * QSCALE : bv[i - 768];
  if (i < 768 * 768)  { int n = i / 768,  k = i % 768;  Wo_t[i] = f2b(Wo[k * 768  + n]); }
  if (i < 3072 * 768) { int n = i / 768,  k = i % 768;  W1_t[i] = f2b(W1[k * 3072 + n]); }
  if (i < 768 * 3072) { int n = i / 3072, k = i % 3072; W2_t[i] = f2b(W2[k * 768  + n]); }
}

// ---------------- LayerNorm: f32 [8192][768] -> bf16 ------------------------
__global__ __launch_bounds__(256) void ln_kernel(
    const float* __restrict__ x, const float* __restrict__ g,
    const float* __restrict__ b, unsigned short* __restrict__ out)
{
  __shared__ float red[4], red2[4];
  int row = blockIdx.x, t = threadIdx.x;
  const float* xr = x + (size_t)row * 768;
  float v0 = xr[t], v1 = xr[t + 256], v2 = xr[t + 512];
  float s = v0 + v1 + v2;
  #pragma unroll
  for (int m = 32; m; m >>= 1) s += __shfl_xor(s, m);
  if ((t & 63) == 0) red[t >> 6] = s;
  __syncthreads();
  float mean = (red[0] + red[1] + red[2] + red[3]) * (1.f / 768.f);
  float d0 = v0 - mean, d1 = v1 - mean, d2 = v2 - mean;
  float vs = d0 * d0 + d1 * d1 + d2 * d2;
  #pragma unroll
  for (int m = 32; m; m >>= 1) vs += __shfl_xor(vs, m);
  if ((t & 63) == 0) red2[t >> 6] = vs;
  __syncthreads();
  float var = (red2[0] + red2[1] + red2[2] + red2[3]) * (1.f / 768.f);
  float rs = rsqrtf(var + 1e-5f);
  unsigned short* o = out + (size_t)row * 768;
  o[t]       = f2b(d0 * rs * g[t]       + b[t]);
  o[t + 256] = f2b(d1 * rs * g[t + 256] + b[t + 256]);
  o[t + 512] = f2b(d2 * rs * g[t + 512] + b[t + 512]);
}

// ---------------- 128x128 2-buf counted-vmcnt GEMM ---------------------------
// 256 thr = 4 waves (2x2), wave 64x64, 4x4 mfma_16x16x32_bf16, BK=64,
// 2 LDS buffers (64 KiB -> 2 blocks/CU).  Per K-tile t:
//   stage(t+1) issue -> vmcnt(8) [waits tile t's 8 loads; t+1 in flight] ->
//   barrier -> ds_read(t) -> setprio(1) 32 MFMA setprio(0) -> barrier.
// Race audit: barrier-2(t-1) orders all waves' reads of buf X before
// stage(t+1) overwrites it; vmcnt(8)+barrier-1 ensures all staging landed.
// Both-sides XOR swizzle; XCD-chunked n-fastest block map.
// EPI: 1 = f32 out = resid + acc + bias; 2 = bf16 tanh-gelu; 3 = qv split.
template<int EPI, int N, int K>
__global__ __launch_bounds__(256, 2) void gemm128(
    const unsigned short* __restrict__ A, const unsigned short* __restrict__ Bt,
    const float* __restrict__ bias,
    const float* resid, float* out_f32,
    unsigned short* __restrict__ out_bf,
    unsigned short* __restrict__ q_out, unsigned short* __restrict__ vt_out)
{
  __shared__ __align__(16) unsigned short As_[2][8192];
  __shared__ __align__(16) unsigned short Bs_[2][8192];
  constexpr int NTN = N >> 7;
  constexpr int NT = K >> 6;
  int bid = blockIdx.x;
  int q8 = gridDim.x >> 3;                      // grids are %8==0
  int sb = (bid & 7) * q8 + (bid >> 3);         // XCD-chunked
  int m0 = (sb / NTN) << 7, n0 = (sb % NTN) << 7;  // n fastest within chunk
  int t = threadIdx.x, lane = t & 63, w = t >> 6;
  int l15 = lane & 15, lg = lane >> 4;
  int wmo = (w >> 1) << 6, wno = (w & 1) << 6;
  int lrow = lane >> 3;
  int lxor = ((lane & 7) ^ lrow) << 3;
  const unsigned short* Abase = A + (size_t)m0 * K;
  const unsigned short* Bbase = Bt + (size_t)n0 * K;

  auto stage = [&](int buf, int tile) {
    int k0 = tile << 6;
    #pragma unroll
    for (int j = 0; j < 4; ++j) {
      int row = j * 32 + w * 8 + lrow;
      int doff = j * 2048 + w * 512;
      g2l16(&Abase[(size_t)row * K + k0 + lxor], &As_[buf][doff]);
      g2l16(&Bbase[(size_t)row * K + k0 + lxor], &Bs_[buf][doff]);
    }
  };

  f32x4 acc[4][4] = {};
  stage(0, 0);
  asm volatile("s_waitcnt vmcnt(0)" ::: "memory");
  __builtin_amdgcn_sched_barrier(0);
  __builtin_amdgcn_s_barrier();

  int cswz = (l15 & 7) << 3;
  for (int tt = 0; tt < NT; ++tt) {
    int cur = tt & 1;
    // issue next tile, then COUNTED wait: tile tt's 8 loads done, tt+1's stay
    if (tt + 1 < NT) {
      stage(cur ^ 1, tt + 1);
      asm volatile("s_waitcnt vmcnt(8)" ::: "memory");
    } else {
      asm volatile("s_waitcnt vmcnt(0)" ::: "memory");
    }
    __builtin_amdgcn_sched_barrier(0);
    __builtin_amdgcn_s_barrier();          // all waves' stage(tt) landed
    __builtin_amdgcn_sched_barrier(0);
    const unsigned short* Ac = &As_[cur][0];
    const unsigned short* Bc = &Bs_[cur][0];
    #pragma unroll
    for (int kk = 0; kk < 2; ++kk) {
      s8v a[4], b[4];
      int col = (kk * 32 + lg * 8) ^ cswz;
      #pragma unroll
      for (int i = 0; i < 4; ++i) {
        a[i] = *(const s8v*)&Ac[(wmo + i * 16 + l15) * 64 + col];
        b[i] = *(const s8v*)&Bc[(wno + i * 16 + l15) * 64 + col];
      }
      __builtin_amdgcn_s_setprio(1);
      #pragma unroll
      for (int mi = 0; mi < 4; ++mi)
        #pragma unroll
        for (int ni = 0; ni < 4; ++ni)
          acc[mi][ni] = __builtin_amdgcn_mfma_f32_16x16x32_bf16(a[mi], b[ni], acc[mi][ni], 0, 0, 0);
      __builtin_amdgcn_s_setprio(0);
    }
    if (tt + 1 < NT) {
      __builtin_amdgcn_sched_barrier(0);
      __builtin_amdgcn_s_barrier();        // reads of buf cur done block-wide
      __builtin_amdgcn_sched_barrier(0);
    }
  }
  // ---- epilogue ----
  #pragma unroll
  for (int mi = 0; mi < 4; ++mi) {
    #pragma unroll
    for (int ni = 0; ni < 4; ++ni) {
      int col = n0 + wno + ni * 16 + l15;
      float bs = bias[col];
      #pragma unroll
      for (int r = 0; r < 4; ++r) {
        int row = m0 + wmo + mi * 16 + lg * 4 + r;
        float v = acc[mi][ni][r] + bs;
        if (EPI == 1) {
          out_f32[(size_t)row * N + col] = resid[(size_t)row * N + col] + v;
        } else if (EPI == 2) {
          // tanh-gelu via exp2: v * sigmoid(1.5957688(v + 0.044715 v^3))
          float v2 = v * v;
          float z = v * fmaf(-0.10294202f, v2, -2.302026f);
          float e; asm("v_exp_f32 %0, %1" : "=v"(e) : "v"(z));
          float rcp; asm("v_rcp_f32 %0, %1" : "=v"(rcp) : "v"(e + 1.0f));
          out_bf[(size_t)row * N + col] = f2b(v * rcp);
        } else { // EPI == 3
          if (col < 768) {
            q_out[(size_t)row * 768 + col] = f2b(v);
          } else {
            int c = col - 768; int hh = c >> 6, e = c & 63;
            int bb = row >> 10, s = row & 1023;
            vt_out[(((size_t)(bb * 12 + hh)) * 64 + e) * 1024 + s] = f2b(v);
          }
        }
      }
    }
  }
}

// ---------------- fused attention (k = q quirk; scale folded into q_bf) ------
__global__ __launch_bounds__(256) void attn_kernel(
    const unsigned short* __restrict__ qk,  // [8192][768] (q == k, pre-scaled)
    const unsigned short* __restrict__ vt,  // [96][64][1024]
    unsigned short* __restrict__ o)         // [8192][768]
{
  __shared__ __align__(16) unsigned short Qs[128 * 64];
  __shared__ __align__(16) unsigned short Ks[2][64 * 64];
  __shared__ __align__(16) unsigned short Vs[2][64 * 64];
  __shared__ __align__(16) unsigned short Ps[128 * 64];
  int bid = blockIdx.x;
  int xcd = bid & 7, idx = bid >> 3;
  int bh = xcd * 12 + (idx >> 3), qt = idx & 7;
  int b = bh / 12, h = bh % 12;
  int t = threadIdx.x, lane = t & 63, w = t >> 6;
  int l15 = lane & 15, lg = lane >> 4;
  int wq0 = w << 5;
  size_t qrow0 = (size_t)b * 1024 + qt * 128;
  size_t krow0 = (size_t)b * 1024;
  size_t vbase = ((size_t)bh) * 64 * 1024;

  int srow = t >> 3;
  int scsw = ((t & 7) << 3) ^ ((srow & 7) << 3);
  const unsigned short* qsrc = &qk[(qrow0 + srow) * 768 + h * 64 + scsw];
  const unsigned short* ksrc = &qk[(krow0 + srow) * 768 + h * 64 + scsw];
  const unsigned short* vsrc = &vt[vbase + (size_t)srow * 1024 + scsw];

  #pragma unroll
  for (int j = 0; j < 4; ++j)
    g2l16(qsrc + (size_t)j * 32 * 768, &Qs[(j * 256 + w * 64) * 8]);
  #pragma unroll
  for (int j = 0; j < 2; ++j) {
    g2l16(ksrc + (size_t)j * 32 * 768, &Ks[0][(j * 256 + w * 64) * 8]);
    g2l16(vsrc + (size_t)j * 32 * 1024, &Vs[0][(j * 256 + w * 64) * 8]);
  }
  asm volatile("s_waitcnt vmcnt(0)" ::: "memory");
  __builtin_amdgcn_s_barrier();

  f32x4 oacc[4][2] = {};
  float lsum[2] = {0.f, 0.f};
  int cswz = (l15 & 7) << 3;

  for (int kt = 0; kt < 16; ++kt) {
    int buf = kt & 1;
    if (kt < 15) {
      const unsigned short* kp = ksrc + (size_t)(kt + 1) * 64 * 768;
      const unsigned short* vp = vsrc + (kt + 1) * 64;
      #pragma unroll
      for (int j = 0; j < 2; ++j) {
        g2l16(kp + (size_t)j * 32 * 768, &Ks[buf ^ 1][(j * 256 + w * 64) * 8]);
        g2l16(vp + (size_t)j * 32 * 1024, &Vs[buf ^ 1][(j * 256 + w * 64) * 8]);
      }
    }
    const unsigned short* Kb = Ks[buf];
    const unsigned short* Vb = Vs[buf];
    f32x4 st[4][2] = {};
    #pragma unroll
    for (int kk = 0; kk < 2; ++kk) {
      int col = (kk * 32 + lg * 8) ^ cswz;
      s8v a[4], bq2[2];
      #pragma unroll
      for (int i = 0; i < 4; ++i) a[i] = *(const s8v*)&Kb[(i * 16 + l15) * 64 + col];
      #pragma unroll
      for (int i = 0; i < 2; ++i) bq2[i] = *(const s8v*)&Qs[(wq0 + i * 16 + l15) * 64 + col];
      #pragma unroll
      for (int mi = 0; mi < 4; ++mi)
        #pragma unroll
        for (int ni = 0; ni < 2; ++ni)
          st[mi][ni] = __builtin_amdgcn_mfma_f32_16x16x32_bf16(a[mi], bq2[ni], st[mi][ni], 0, 0, 0);
    }
    #pragma unroll
    for (int ni = 0; ni < 2; ++ni) {
      int prow = (wq0 + ni * 16 + l15) * 64;
      #pragma unroll
      for (int mi = 0; mi < 4; ++mi) {
        float p0, p1, p2, p3;
        asm("v_exp_f32 %0, %1" : "=v"(p0) : "v"(st[mi][ni][0]));
        asm("v_exp_f32 %0, %1" : "=v"(p1) : "v"(st[mi][ni][1]));
        asm("v_exp_f32 %0, %1" : "=v"(p2) : "v"(st[mi][ni][2]));
        asm("v_exp_f32 %0, %1" : "=v"(p3) : "v"(st[mi][ni][3]));
        lsum[ni] += (p0 + p1) + (p2 + p3);
        unsigned lo, hi;
        asm("v_cvt_pk_bf16_f32 %0, %1, %2" : "=v"(lo) : "v"(p0), "v"(p1));
        asm("v_cvt_pk_bf16_f32 %0, %1, %2" : "=v"(hi) : "v"(p2), "v"(p3));
        unsigned long long pk = (unsigned long long)lo | ((unsigned long long)hi << 32);
        *(unsigned long long*)&Ps[prow + ((mi * 16 + lg * 4) ^ cswz)] = pk;
      }
    }
    #pragma unroll
    for (int kk = 0; kk < 2; ++kk) {
      int col = (kk * 32 + lg * 8) ^ cswz;
      s8v a[4], bp[2];
      #pragma unroll
      for (int i = 0; i < 4; ++i) a[i] = *(const s8v*)&Vb[(i * 16 + l15) * 64 + col];
      #pragma unroll
      for (int i = 0; i < 2; ++i) bp[i] = *(const s8v*)&Ps[(wq0 + i * 16 + l15) * 64 + col];
      #pragma unroll
      for (int ei = 0; ei < 4; ++ei)
        #pragma unroll
        for (int ni = 0; ni < 2; ++ni)
          oacc[ei][ni] = __builtin_amdgcn_mfma_f32_16x16x32_bf16(a[ei], bp[ni], oacc[ei][ni], 0, 0, 0);
    }
    asm volatile("s_waitcnt vmcnt(0)" ::: "memory");
    __builtin_amdgcn_s_barrier();
  }
  #pragma unroll
  for (int ni = 0; ni < 2; ++ni) {
    float s = lsum[ni];
    s += __shfl_xor(s, 16);
    s += __shfl_xor(s, 32);
    float inv = 1.f / s;
    int q = wq0 + ni * 16 + l15;
    size_t obase = (qrow0 + q) * 768 + h * 64;
    #pragma unroll
    for (int ei = 0; ei < 4; ++ei) {
      us4v ov;
      #pragma unroll
      for (int r = 0; r < 4; ++r) ov[r] = f2b(oacc[ei][ni][r] * inv);
      *(us4v*)&o[obase + ei * 16 + lg * 4] = ov;
    }
  }
}

// ---------------------------------------------------------------------------
extern "C" void kernel_launch(void* const* d_in, const int* in_sizes, int n_in,
                              void* d_out, int out_size, void* d_ws, size_t ws_size,
                              hipStream_t stream)
{
  const float* x     = (const float*)d_in[0];
  const float* ln1_g = (const float*)d_in[1];
  const float* ln1_b = (const float*)d_in[2];
  const float* Wq    = (const float*)d_in[3];
  const float* bq    = (const float*)d_in[4];
  const float* Wv    = (const float*)d_in[5];
  const float* bv    = (const float*)d_in[6];
  const float* Wo    = (const float*)d_in[7];
  const float* bo    = (const float*)d_in[8];
  const float* ln2_g = (const float*)d_in[9];
  const float* ln2_b = (const float*)d_in[10];
  const float* W1    = (const float*)d_in[11];
  const float* b1    = (const float*)d_in[12];
  const float* W2    = (const float*)d_in[13];
  const float* b2    = (const float*)d_in[14];
  float* out = (float*)d_out;

  char* ws = (char*)d_ws;
  size_t off = 0;
  auto alloc = [&](size_t bytes) -> void* {
    void* p = ws + off; off += (bytes + 255) & ~(size_t)255; return p;
  };
  unsigned short* Wqv_t  = (unsigned short*)alloc(1536ull * 768 * 2);
  float*          bias_qv= (float*)         alloc(1536ull * 4);
  unsigned short* Wo_t   = (unsigned short*)alloc(768ull * 768 * 2);
  unsigned short* W1_t   = (unsigned short*)alloc(3072ull * 768 * 2);
  unsigned short* W2_t   = (unsigned short*)alloc(768ull * 3072 * 2);
  unsigned short* h_bf   = (unsigned short*)alloc(8192ull * 768 * 2);
  unsigned short* q_bf   = (unsigned short*)alloc(8192ull * 768 * 2);
  unsigned short* v_t    = (unsigned short*)alloc(96ull * 64 * 1024 * 2);
  unsigned short* o_bf   = (unsigned short*)alloc(8192ull * 768 * 2);
  unsigned short* h2_bf  = (unsigned short*)alloc(8192ull * 768 * 2);
  unsigned short* m1_bf  = (unsigned short*)alloc(8192ull * 3072 * 2);

  repack_kernel<<<9216, 256, 0, stream>>>(Wq, bq, Wv, bv, Wo, W1, W2,
                                          Wqv_t, bias_qv, Wo_t, W1_t, W2_t);
  ln_kernel<<<8192, 256, 0, stream>>>(x, ln1_g, ln1_b, h_bf);
  gemm128<3, 1536, 768><<<768, 256, 0, stream>>>(h_bf, Wqv_t, bias_qv,
      nullptr, nullptr, nullptr, q_bf, v_t);
  attn_kernel<<<768, 256, 0, stream>>>(q_bf, v_t, o_bf);
  gemm128<1, 768, 768><<<384, 256, 0, stream>>>(o_bf, Wo_t, bo,
      x, out, nullptr, nullptr, nullptr);
  ln_kernel<<<8192, 256, 0, stream>>>(out, ln2_g, ln2_b, h2_bf);
  gemm128<2, 3072, 768><<<1536, 256, 0, stream>>>(h2_bf, W1_t, b1,
      nullptr, nullptr, m1_bf, nullptr, nullptr);
  gemm128<1, 768, 3072><<<384, 256, 0, stream>>>(m1_bf, W2_t, b2,
      out, out, nullptr, nullptr, nullptr);
}

// Round 9
// 278.292 us; speedup vs baseline: 1.3182x; 1.1075x over previous
//
#include <hip/hip_runtime.h>
#include <stdint.h>

// ---------------------------------------------------------------------------
// Encoder block, MI355X bf16-MFMA (round 9: 8-wave 128x128 GEMM, 2 LDS
// buffers, 2 blocks/CU -> 16 waves/CU, counted vmcnt(4) pipeline).
// Quirks: k = q (query projection), scale = 768^-0.5.
// ---------------------------------------------------------------------------

typedef __attribute__((ext_vector_type(8))) short s8v;      // 8 x bf16
typedef __attribute__((ext_vector_type(4))) float f32x4;    // MFMA C/D frag
typedef __attribute__((ext_vector_type(4))) unsigned short us4v;

__device__ __forceinline__ unsigned short f2b(float f) {  // f32 -> bf16 RTNE
  union { float f; unsigned u; } v; v.f = f;
  unsigned r = v.u + 0x7FFFu + ((v.u >> 16) & 1u);
  return (unsigned short)(r >> 16);
}

__device__ __forceinline__ void g2l16(const unsigned short* g, unsigned short* l) {
  __builtin_amdgcn_global_load_lds(
      (const __attribute__((address_space(1))) unsigned int*)g,
      (__attribute__((address_space(3))) unsigned int*)l, 16, 0, 0);
}

// sqrt(768^-0.5 * log2(e)): folded into BOTH q and k (same tensor, k=q quirk)
#define QSCALE 0.22816534f

// ---------------- weight repack: all weights -> bf16, B^T [N][K] layout ------
__global__ __launch_bounds__(256) void repack_kernel(
    const float* __restrict__ Wq, const float* __restrict__ bq,
    const float* __restrict__ Wv, const float* __restrict__ bv,
    const float* __restrict__ Wo, const float* __restrict__ W1,
    const float* __restrict__ W2,
    unsigned short* __restrict__ Wqv_t, float* __restrict__ bias_qv,
    unsigned short* __restrict__ Wo_t, unsigned short* __restrict__ W1_t,
    unsigned short* __restrict__ W2_t)
{
  int i = blockIdx.x * 256 + threadIdx.x;
  if (i < 1536 * 768) {
    int n = i / 768, d = i % 768;
    float val;
    if (n < 768) { int h = n >> 6, e = n & 63; val = Wq[(h * 768 + d) * 64 + e] * QSCALE; }
    else { int c = n - 768; int h = c >> 6, e = c & 63; val = Wv[(h * 768 + d) * 64 + e]; }
    Wqv_t[i] = f2b(val);
  }
  if (i < 1536) bias_qv[i] = (i < 768) ? bq[i] * QSCALE : bv[i - 768];
  if (i < 768 * 768)  { int n = i / 768,  k = i % 768;  Wo_t[i] = f2b(Wo[k * 768  + n]); }
  if (i < 3072 * 768) { int n = i / 768,  k = i % 768;  W1_t[i] = f2b(W1[k * 3072 + n]); }
  if (i < 768 * 3072) { int n = i / 3072, k = i % 3072; W2_t[i] = f2b(W2[k * 768  + n]); }
}

// ---------------- LayerNorm: f32 [8192][768] -> bf16 ------------------------
__global__ __launch_bounds__(256) void ln_kernel(
    const float* __restrict__ x, const float* __restrict__ g,
    const float* __restrict__ b, unsigned short* __restrict__ out)
{
  __shared__ float red[4], red2[4];
  int row = blockIdx.x, t = threadIdx.x;
  const float* xr = x + (size_t)row * 768;
  float v0 = xr[t], v1 = xr[t + 256], v2 = xr[t + 512];
  float s = v0 + v1 + v2;
  #pragma unroll
  for (int m = 32; m; m >>= 1) s += __shfl_xor(s, m);
  if ((t & 63) == 0) red[t >> 6] = s;
  __syncthreads();
  float mean = (red[0] + red[1] + red[2] + red[3]) * (1.f / 768.f);
  float d0 = v0 - mean, d1 = v1 - mean, d2 = v2 - mean;
  float vs = d0 * d0 + d1 * d1 + d2 * d2;
  #pragma unroll
  for (int m = 32; m; m >>= 1) vs += __shfl_xor(vs, m);
  if ((t & 63) == 0) red2[t >> 6] = vs;
  __syncthreads();
  float var = (red2[0] + red2[1] + red2[2] + red2[3]) * (1.f / 768.f);
  float rs = rsqrtf(var + 1e-5f);
  unsigned short* o = out + (size_t)row * 768;
  o[t]       = f2b(d0 * rs * g[t]       + b[t]);
  o[t + 256] = f2b(d1 * rs * g[t + 256] + b[t + 256]);
  o[t + 512] = f2b(d2 * rs * g[t + 512] + b[t + 512]);
}

// ---------------- 8-wave 128x128 2-buf counted-vmcnt GEMM --------------------
// 512 thr = 8 waves (2m x 4n), wave tile 64x32 (acc 4x2), BK=64.
// 2 LDS buffers (64 KiB -> 2 blocks/CU = 16 waves/CU).  Per K-tile t:
//   stage(t+1) [4 loads/thr] -> vmcnt(4) [tile t done; t+1 in flight] ->
//   barrier -> ds_read(t) [12 b128] -> setprio(1) 16 MFMA setprio(0) -> barrier.
// Race audit: barrier-2(t-1) orders all waves' reads of buf X before
// stage(t+1) overwrites it; vmcnt(4)+barrier-1 ensures all staging landed.
// Both-sides XOR swizzle; XCD-chunked n-fastest block map.
// EPI: 1 = f32 out = resid + acc + bias; 2 = bf16 tanh-gelu; 3 = qv split.
template<int EPI, int N, int K>
__global__ __launch_bounds__(512, 4) void gemm128(
    const unsigned short* __restrict__ A, const unsigned short* __restrict__ Bt,
    const float* __restrict__ bias,
    const float* resid, float* out_f32,
    unsigned short* __restrict__ out_bf,
    unsigned short* __restrict__ q_out, unsigned short* __restrict__ vt_out)
{
  __shared__ __align__(16) unsigned short As_[2][8192];
  __shared__ __align__(16) unsigned short Bs_[2][8192];
  constexpr int NTN = N >> 7;
  constexpr int NT = K >> 6;
  int bid = blockIdx.x;
  int q8 = gridDim.x >> 3;                      // grids are %8==0
  int sb = (bid & 7) * q8 + (bid >> 3);         // XCD-chunked
  int m0 = (sb / NTN) << 7, n0 = (sb % NTN) << 7;  // n fastest within chunk
  int t = threadIdx.x, lane = t & 63, w = t >> 6;  // w 0..7
  int l15 = lane & 15, lg = lane >> 4;
  int wm = (w >> 2) << 6;                       // 0 / 64
  int wn = (w & 3) << 5;                        // 0 / 32 / 64 / 96
  int lrow = lane >> 3;                         // 0..7
  int lxor = ((lane & 7) ^ lrow) << 3;          // pre-swizzled src col (ushort)
  const unsigned short* Abase = A + (size_t)m0 * K;
  const unsigned short* Bbase = Bt + (size_t)n0 * K;

  auto stage = [&](int buf, int tile) {
    int k0 = tile << 6;
    #pragma unroll
    for (int j = 0; j < 2; ++j) {               // 4 loads/thread: A,B x j
      int row = j * 64 + w * 8 + lrow;
      int doff = (j * 512 + w * 64) * 8;        // wave-uniform dest (ushort)
      g2l16(&Abase[(size_t)row * K + k0 + lxor], &As_[buf][doff]);
      g2l16(&Bbase[(size_t)row * K + k0 + lxor], &Bs_[buf][doff]);
    }
  };

  f32x4 acc[4][2] = {};
  stage(0, 0);
  asm volatile("s_waitcnt vmcnt(0)" ::: "memory");
  __builtin_amdgcn_sched_barrier(0);
  __builtin_amdgcn_s_barrier();

  int cswz = (l15 & 7) << 3;
  for (int tt = 0; tt < NT; ++tt) {
    int cur = tt & 1;
    // issue next tile, then COUNTED wait: tile tt's loads done, tt+1's stay
    if (tt + 1 < NT) {
      stage(cur ^ 1, tt + 1);
      asm volatile("s_waitcnt vmcnt(4)" ::: "memory");
    } else {
      asm volatile("s_waitcnt vmcnt(0)" ::: "memory");
    }
    __builtin_amdgcn_sched_barrier(0);
    __builtin_amdgcn_s_barrier();          // all waves' stage(tt) landed
    __builtin_amdgcn_sched_barrier(0);
    const unsigned short* Ac = &As_[cur][0];
    const unsigned short* Bc = &Bs_[cur][0];
    #pragma unroll
    for (int kk = 0; kk < 2; ++kk) {
      s8v a[4], b[2];
      int col = (kk * 32 + lg * 8) ^ cswz;
      #pragma unroll
      for (int i = 0; i < 4; ++i)
        a[i] = *(const s8v*)&Ac[(wm + i * 16 + l15) * 64 + col];
      #pragma unroll
      for (int i = 0; i < 2; ++i)
        b[i] = *(const s8v*)&Bc[(wn + i * 16 + l15) * 64 + col];
      __builtin_amdgcn_s_setprio(1);
      #pragma unroll
      for (int mi = 0; mi < 4; ++mi)
        #pragma unroll
        for (int ni = 0; ni < 2; ++ni)
          acc[mi][ni] = __builtin_amdgcn_mfma_f32_16x16x32_bf16(a[mi], b[ni], acc[mi][ni], 0, 0, 0);
      __builtin_amdgcn_s_setprio(0);
    }
    if (tt + 1 < NT) {
      __builtin_amdgcn_sched_barrier(0);
      __builtin_amdgcn_s_barrier();        // reads of buf cur done block-wide
      __builtin_amdgcn_sched_barrier(0);
    }
  }
  // ---- epilogue ----
  #pragma unroll
  for (int mi = 0; mi < 4; ++mi) {
    #pragma unroll
    for (int ni = 0; ni < 2; ++ni) {
      int col = n0 + wn + ni * 16 + l15;
      float bs = bias[col];
      #pragma unroll
      for (int r = 0; r < 4; ++r) {
        int row = m0 + wm + mi * 16 + lg * 4 + r;
        float v = acc[mi][ni][r] + bs;
        if (EPI == 1) {
          out_f32[(size_t)row * N + col] = resid[(size_t)row * N + col] + v;
        } else if (EPI == 2) {
          // tanh-gelu via exp2: v * sigmoid(1.5957688(v + 0.044715 v^3))
          float v2 = v * v;
          float z = v * fmaf(-0.10294202f, v2, -2.302026f);
          float e; asm("v_exp_f32 %0, %1" : "=v"(e) : "v"(z));
          float rcp; asm("v_rcp_f32 %0, %1" : "=v"(rcp) : "v"(e + 1.0f));
          out_bf[(size_t)row * N + col] = f2b(v * rcp);
        } else { // EPI == 3
          if (col < 768) {
            q_out[(size_t)row * 768 + col] = f2b(v);
          } else {
            int c = col - 768; int hh = c >> 6, e = c & 63;
            int bb = row >> 10, s = row & 1023;
            vt_out[(((size_t)(bb * 12 + hh)) * 64 + e) * 1024 + s] = f2b(v);
          }
        }
      }
    }
  }
}

// ---------------- fused attention (k = q quirk; scale folded into q_bf) ------
__global__ __launch_bounds__(256) void attn_kernel(
    const unsigned short* __restrict__ qk,  // [8192][768] (q == k, pre-scaled)
    const unsigned short* __restrict__ vt,  // [96][64][1024]
    unsigned short* __restrict__ o)         // [8192][768]
{
  __shared__ __align__(16) unsigned short Qs[128 * 64];
  __shared__ __align__(16) unsigned short Ks[2][64 * 64];
  __shared__ __align__(16) unsigned short Vs[2][64 * 64];
  __shared__ __align__(16) unsigned short Ps[128 * 64];
  int bid = blockIdx.x;
  int xcd = bid & 7, idx = bid >> 3;
  int bh = xcd * 12 + (idx >> 3), qt = idx & 7;
  int b = bh / 12, h = bh % 12;
  int t = threadIdx.x, lane = t & 63, w = t >> 6;
  int l15 = lane & 15, lg = lane >> 4;
  int wq0 = w << 5;
  size_t qrow0 = (size_t)b * 1024 + qt * 128;
  size_t krow0 = (size_t)b * 1024;
  size_t vbase = ((size_t)bh) * 64 * 1024;

  int srow = t >> 3;
  int scsw = ((t & 7) << 3) ^ ((srow & 7) << 3);
  const unsigned short* qsrc = &qk[(qrow0 + srow) * 768 + h * 64 + scsw];
  const unsigned short* ksrc = &qk[(krow0 + srow) * 768 + h * 64 + scsw];
  const unsigned short* vsrc = &vt[vbase + (size_t)srow * 1024 + scsw];

  #pragma unroll
  for (int j = 0; j < 4; ++j)
    g2l16(qsrc + (size_t)j * 32 * 768, &Qs[(j * 256 + w * 64) * 8]);
  #pragma unroll
  for (int j = 0; j < 2; ++j) {
    g2l16(ksrc + (size_t)j * 32 * 768, &Ks[0][(j * 256 + w * 64) * 8]);
    g2l16(vsrc + (size_t)j * 32 * 1024, &Vs[0][(j * 256 + w * 64) * 8]);
  }
  asm volatile("s_waitcnt vmcnt(0)" ::: "memory");
  __builtin_amdgcn_s_barrier();

  f32x4 oacc[4][2] = {};
  float lsum[2] = {0.f, 0.f};
  int cswz = (l15 & 7) << 3;

  for (int kt = 0; kt < 16; ++kt) {
    int buf = kt & 1;
    if (kt < 15) {
      const unsigned short* kp = ksrc + (size_t)(kt + 1) * 64 * 768;
      const unsigned short* vp = vsrc + (kt + 1) * 64;
      #pragma unroll
      for (int j = 0; j < 2; ++j) {
        g2l16(kp + (size_t)j * 32 * 768, &Ks[buf ^ 1][(j * 256 + w * 64) * 8]);
        g2l16(vp + (size_t)j * 32 * 1024, &Vs[buf ^ 1][(j * 256 + w * 64) * 8]);
      }
    }
    const unsigned short* Kb = Ks[buf];
    const unsigned short* Vb = Vs[buf];
    f32x4 st[4][2] = {};
    #pragma unroll
    for (int kk = 0; kk < 2; ++kk) {
      int col = (kk * 32 + lg * 8) ^ cswz;
      s8v a[4], bq2[2];
      #pragma unroll
      for (int i = 0; i < 4; ++i) a[i] = *(const s8v*)&Kb[(i * 16 + l15) * 64 + col];
      #pragma unroll
      for (int i = 0; i < 2; ++i) bq2[i] = *(const s8v*)&Qs[(wq0 + i * 16 + l15) * 64 + col];
      #pragma unroll
      for (int mi = 0; mi < 4; ++mi)
        #pragma unroll
        for (int ni = 0; ni < 2; ++ni)
          st[mi][ni] = __builtin_amdgcn_mfma_f32_16x16x32_bf16(a[mi], bq2[ni], st[mi][ni], 0, 0, 0);
    }
    #pragma unroll
    for (int ni = 0; ni < 2; ++ni) {
      int prow = (wq0 + ni * 16 + l15) * 64;
      #pragma unroll
      for (int mi = 0; mi < 4; ++mi) {
        float p0, p1, p2, p3;
        asm("v_exp_f32 %0, %1" : "=v"(p0) : "v"(st[mi][ni][0]));
        asm("v_exp_f32 %0, %1" : "=v"(p1) : "v"(st[mi][ni][1]));
        asm("v_exp_f32 %0, %1" : "=v"(p2) : "v"(st[mi][ni][2]));
        asm("v_exp_f32 %0, %1" : "=v"(p3) : "v"(st[mi][ni][3]));
        lsum[ni] += (p0 + p1) + (p2 + p3);
        unsigned lo, hi;
        asm("v_cvt_pk_bf16_f32 %0, %1, %2" : "=v"(lo) : "v"(p0), "v"(p1));
        asm("v_cvt_pk_bf16_f32 %0, %1, %2" : "=v"(hi) : "v"(p2), "v"(p3));
        unsigned long long pk = (unsigned long long)lo | ((unsigned long long)hi << 32);
        *(unsigned long long*)&Ps[prow + ((mi * 16 + lg * 4) ^ cswz)] = pk;
      }
    }
    #pragma unroll
    for (int kk = 0; kk < 2; ++kk) {
      int col = (kk * 32 + lg * 8) ^ cswz;
      s8v a[4], bp[2];
      #pragma unroll
      for (int i = 0; i < 4; ++i) a[i] = *(const s8v*)&Vb[(i * 16 + l15) * 64 + col];
      #pragma unroll
      for (int i = 0; i < 2; ++i) bp[i] = *(const s8v*)&Ps[(wq0 + i * 16 + l15) * 64 + col];
      #pragma unroll
      for (int ei = 0; ei < 4; ++ei)
        #pragma unroll
        for (int ni = 0; ni < 2; ++ni)
          oacc[ei][ni] = __builtin_amdgcn_mfma_f32_16x16x32_bf16(a[ei], bp[ni], oacc[ei][ni], 0, 0, 0);
    }
    asm volatile("s_waitcnt vmcnt(0)" ::: "memory");
    __builtin_amdgcn_s_barrier();
  }
  #pragma unroll
  for (int ni = 0; ni < 2; ++ni) {
    float s = lsum[ni];
    s += __shfl_xor(s, 16);
    s += __shfl_xor(s, 32);
    float inv = 1.f / s;
    int q = wq0 + ni * 16 + l15;
    size_t obase = (qrow0 + q) * 768 + h * 64;
    #pragma unroll
    for (int ei = 0; ei < 4; ++ei) {
      us4v ov;
      #pragma unroll
      for (int r = 0; r < 4; ++r) ov[r] = f2b(oacc[ei][ni][r] * inv);
      *(us4v*)&o[obase + ei * 16 + lg * 4] = ov;
    }
  }
}

// ---------------------------------------------------------------------------
extern "C" void kernel_launch(void* const* d_in, const int* in_sizes, int n_in,
                              void* d_out, int out_size, void* d_ws, size_t ws_size,
                              hipStream_t stream)
{
  const float* x     = (const float*)d_in[0];
  const float* ln1_g = (const float*)d_in[1];
  const float* ln1_b = (const float*)d_in[2];
  const float* Wq    = (const float*)d_in[3];
  const float* bq    = (const float*)d_in[4];
  const float* Wv    = (const float*)d_in[5];
  const float* bv    = (const float*)d_in[6];
  const float* Wo    = (const float*)d_in[7];
  const float* bo    = (const float*)d_in[8];
  const float* ln2_g = (const float*)d_in[9];
  const float* ln2_b = (const float*)d_in[10];
  const float* W1    = (const float*)d_in[11];
  const float* b1    = (const float*)d_in[12];
  const float* W2    = (const float*)d_in[13];
  const float* b2    = (const float*)d_in[14];
  float* out = (float*)d_out;

  char* ws = (char*)d_ws;
  size_t off = 0;
  auto alloc = [&](size_t bytes) -> void* {
    void* p = ws + off; off += (bytes + 255) & ~(size_t)255; return p;
  };
  unsigned short* Wqv_t  = (unsigned short*)alloc(1536ull * 768 * 2);
  float*          bias_qv= (float*)         alloc(1536ull * 4);
  unsigned short* Wo_t   = (unsigned short*)alloc(768ull * 768 * 2);
  unsigned short* W1_t   = (unsigned short*)alloc(3072ull * 768 * 2);
  unsigned short* W2_t   = (unsigned short*)alloc(768ull * 3072 * 2);
  unsigned short* h_bf   = (unsigned short*)alloc(8192ull * 768 * 2);
  unsigned short* q_bf   = (unsigned short*)alloc(8192ull * 768 * 2);
  unsigned short* v_t    = (unsigned short*)alloc(96ull * 64 * 1024 * 2);
  unsigned short* o_bf   = (unsigned short*)alloc(8192ull * 768 * 2);
  unsigned short* h2_bf  = (unsigned short*)alloc(8192ull * 768 * 2);
  unsigned short* m1_bf  = (unsigned short*)alloc(8192ull * 3072 * 2);

  repack_kernel<<<9216, 256, 0, stream>>>(Wq, bq, Wv, bv, Wo, W1, W2,
                                          Wqv_t, bias_qv, Wo_t, W1_t, W2_t);
  ln_kernel<<<8192, 256, 0, stream>>>(x, ln1_g, ln1_b, h_bf);
  gemm128<3, 1536, 768><<<768, 512, 0, stream>>>(h_bf, Wqv_t, bias_qv,
      nullptr, nullptr, nullptr, q_bf, v_t);
  attn_kernel<<<768, 256, 0, stream>>>(q_bf, v_t, o_bf);
  gemm128<1, 768, 768><<<384, 512, 0, stream>>>(o_bf, Wo_t, bo,
      x, out, nullptr, nullptr, nullptr);
  ln_kernel<<<8192, 256, 0, stream>>>(out, ln2_g, ln2_b, h2_bf);
  gemm128<2, 3072, 768><<<1536, 512, 0, stream>>>(h2_bf, W1_t, b1,
      nullptr, nullptr, m1_bf, nullptr, nullptr);
  gemm128<1, 768, 3072><<<384, 512, 0, stream>>>(m1_bf, W2_t, b2,
      out, out, nullptr, nullptr, nullptr);
}